// Round 9
// baseline (226.953 us; speedup 1.0000x reference)
//
#include <hip/hip_runtime.h>

// Problem constants (match reference)
#define H_    64
#define W_    1024
#define NPT   65536            // H*W
#define NTOT  131072           // B*NPT
#define C1_   64
#define C2_   128
#define CIN_  192
#define CM_   128
#define NS_   3
#define DIST2_ 10000.0f
#define BN_EPS_ 1e-5f
#define NSLOT 32               // BN-stat accumulator slots

typedef __attribute__((ext_vector_type(8))) short short8;   // 8 bf16
typedef __attribute__((ext_vector_type(4))) float floatx4;  // MFMA C/D

static __device__ __forceinline__ unsigned short f2bf(float f) {
    unsigned int u = __float_as_uint(f);
    u += 0x7fffu + ((u >> 16) & 1u);      // round-nearest-even
    return (unsigned short)(u >> 16);
}
static __device__ __forceinline__ float bflo(unsigned u) { return __uint_as_float(u << 16); }
static __device__ __forceinline__ float bfhi(unsigned u) { return __uint_as_float(u & 0xffff0000u); }
static __device__ __forceinline__ unsigned packbf(float a, float b) {
    return (unsigned)f2bf(a) | ((unsigned)f2bf(b) << 16);
}

// ---------------------------------------------------------------------------
// K0: fragment-major bf16 weights (coalesced 1KB B-frag wave loads).
// ---------------------------------------------------------------------------
__global__ __launch_bounds__(256) void prepw_kernel(
    const float* __restrict__ w0, const float* __restrict__ w1,
    unsigned short* __restrict__ w0F, unsigned short* __restrict__ w1F)
{
    int tid = blockIdx.x * 256 + threadIdx.x;
    if (tid < 3072) {                       // w0F: 6kk x 8nt x 64lane chunks
        int c = tid, lane = c & 63, nt = (c >> 6) & 7, kk = c >> 9;
        int n = nt * 16 + (lane & 15);
        int kb = kk * 32 + (lane >> 4) * 8;
        #pragma unroll
        for (int j = 0; j < 8; j++)
            w0F[(size_t)c * 8 + j] = f2bf(w0[(size_t)(kb + j) * CM_ + n]);
    } else if (tid < 5120) {                // w1F: 4kk x 8nt x 64lane
        int c = tid - 3072, lane = c & 63, nt = (c >> 6) & 7, kk = c >> 9;
        int n = nt * 16 + (lane & 15);
        int kb = kk * 32 + (lane >> 4) * 8;
        #pragma unroll
        for (int j = 0; j < 8; j++)
            w1F[(size_t)c * 8 + j] = f2bf(w1[(size_t)(kb + j) * CM_ + n]);
    }
}

// ---------------------------------------------------------------------------
// K1: 128 points/block. Inline KNN (threads 0..127, one point each,
// reference 5x5 row-major scan) -> LDS sel/wgt; gather+interp staged via LDS
// (coalesced channel-major); feat1 direct to A-frags; MFMA with frag-major
// w0F, 2-tile B-reuse; y0 frag-packed bf16; BN0 stats on rounded values.
// ---------------------------------------------------------------------------
__global__ __launch_bounds__(256, 3) void fused1_kernel(
    const float* __restrict__ xyz1, const float* __restrict__ xyz2,
    const float* __restrict__ feat1, const float* __restrict__ feat2,
    const unsigned short* __restrict__ w0F, const float* __restrict__ b0,
    uint2* __restrict__ y0w, float* __restrict__ slots0)
{
    __shared__ unsigned short xstage[128][CM_ + 8];  // interp channels, pitch 136
    __shared__ int   selL[128][NS_];
    __shared__ float wgtL[128][NS_];
    __shared__ float wsum[4][CM_], wsq[4][CM_];

    const int t = threadIdx.x;
    const int blk = blockIdx.x;                 // 1024 blocks
    const int pbase = blk * 128;
    const int bidx = blk >> 9;                  // 512 blocks per batch
    const int wv = t >> 6, lane = t & 63;
    const int m = lane & 15, q = lane >> 4;
    const int row0 = pbase + wv * 16 + m;       // tile0 row
    const int row1 = row0 + 64;                 // tile1 row

    // ---- inline KNN: threads 0..127, one point each ----
    if (t < 128) {
        int pt = pbase + t;
        int n = pt & (NPT - 1);
        int h = n >> 10, w = n & (W_ - 1);
        const float* p1 = xyz1 + (size_t)pt * 3;
        float x1 = p1[0], y1 = p1[1], z1 = p1[2];
        const float* x2b = xyz2 + (size_t)bidx * NPT * 3;
        int s0 = 0, s1 = 0, s2 = 0;
        float d0 = 0.f, d1 = 0.f, d2 = 0.f;
        int cnt = 0;
        for (int dh = -2; dh <= 2; dh++) {
            int nh = h + dh;
            bool okh = (nh >= 0) && (nh < H_);
            for (int dw = -2; dw <= 2; dw++) {
                int nw = w + dw;
                if (!(okh && nw >= 0 && nw < W_)) continue;
                int nidx = nh * W_ + nw;
                const float* p2 = x2b + (size_t)nidx * 3;
                float dx = p2[0] - x1, dy = p2[1] - y1, dz = p2[2] - z1;
                float sq = dx * dx + dy * dy + dz * dz;
                if (sq < DIST2_ && cnt < NS_) {
                    if (cnt == 0)      { s0 = nidx; d0 = sq; }
                    else if (cnt == 1) { s1 = nidx; d1 = sq; }
                    else               { s2 = nidx; d2 = sq; }
                    cnt++;
                }
            }
        }
        float self2 = x1 * x1 + y1 * y1 + z1 * z1;
        float dd0 = (cnt > 0) ? d0 : self2;
        float dd1 = (cnt > 1) ? d1 : self2;
        float dd2 = (cnt > 2) ? d2 : self2;
        dd0 = fmaxf(dd0, 1e-10f); dd1 = fmaxf(dd1, 1e-10f); dd2 = fmaxf(dd2, 1e-10f);
        float i0 = 1.0f / dd0, i1 = 1.0f / dd1, i2 = 1.0f / dd2;
        float norm = i0 + i1 + i2;
        selL[t][0] = (cnt > 0) ? s0 : 0;
        selL[t][1] = (cnt > 1) ? s1 : 0;
        selL[t][2] = (cnt > 2) ? s2 : 0;
        wgtL[t][0] = (cnt > 0) ? i0 / norm : 0.f;
        wgtL[t][1] = (cnt > 1) ? i1 / norm : 0.f;
        wgtL[t][2] = (cnt > 2) ? i2 / norm : 0.f;
    }

    // feat1 -> A-frags kk=0,1 for both tiles, directly from global
    short8 af0[2], af1[2];
    #pragma unroll
    for (int kk = 0; kk < 2; kk++) {
        const float* s0p = feat1 + (size_t)row0 * C1_ + kk * 32 + q * 8;
        const float* s1p = feat1 + (size_t)row1 * C1_ + kk * 32 + q * 8;
        float4 fa = *(const float4*)(s0p), fb = *(const float4*)(s0p + 4);
        float4 ga = *(const float4*)(s1p), gb = *(const float4*)(s1p + 4);
        short8 a, b;
        a[0] = f2bf(fa.x); a[1] = f2bf(fa.y); a[2] = f2bf(fa.z); a[3] = f2bf(fa.w);
        a[4] = f2bf(fb.x); a[5] = f2bf(fb.y); a[6] = f2bf(fb.z); a[7] = f2bf(fb.w);
        b[0] = f2bf(ga.x); b[1] = f2bf(ga.y); b[2] = f2bf(ga.z); b[3] = f2bf(ga.w);
        b[4] = f2bf(gb.x); b[5] = f2bf(gb.y); b[6] = f2bf(gb.z); b[7] = f2bf(gb.w);
        af0[kk] = a; af1[kk] = b;
    }
    __syncthreads();

    // IDW interp -> xstage (coalesced: 32 lanes span one row's 128 channels)
    const float* f2b = feat2 + (size_t)bidx * NPT * C2_;
    #pragma unroll
    for (int i = 0; i < 16; i++) {
        int idx = t + i * 256;
        int p = idx >> 5, c4 = (idx & 31) << 2;
        float ax = 0.f, ay = 0.f, az = 0.f, aw = 0.f;
        #pragma unroll
        for (int j = 0; j < NS_; j++) {
            float wj = wgtL[p][j];
            const float4 f = *(const float4*)(f2b + (size_t)selL[p][j] * C2_ + c4);
            ax += wj * f.x; ay += wj * f.y; az += wj * f.z; aw += wj * f.w;
        }
        ushort4 u;
        u.x = f2bf(ax); u.y = f2bf(ay); u.z = f2bf(az); u.w = f2bf(aw);
        *(ushort4*)&xstage[p][c4] = u;
    }
    __syncthreads();

    floatx4 acc0[8], acc1[8];
    #pragma unroll
    for (int nt = 0; nt < 8; nt++) {
        acc0[nt] = (floatx4){0.f, 0.f, 0.f, 0.f};
        acc1[nt] = (floatx4){0.f, 0.f, 0.f, 0.f};
    }

    const int lr0 = wv * 16 + m, lr1 = lr0 + 64;
    #pragma unroll
    for (int kk = 0; kk < 6; kk++) {
        short8 bw[8];                           // prefetch all 8 B-frags
        #pragma unroll
        for (int nt = 0; nt < 8; nt++)
            bw[nt] = *(const short8*)(w0F + ((size_t)(kk * 8 + nt) * 64 + lane) * 8);
        short8 a0, a1;
        if (kk < 2) { a0 = af0[kk]; a1 = af1[kk]; }
        else {
            a0 = *(const short8*)&xstage[lr0][(kk - 2) * 32 + q * 8];
            a1 = *(const short8*)&xstage[lr1][(kk - 2) * 32 + q * 8];
        }
        #pragma unroll
        for (int nt = 0; nt < 8; nt++) {
            acc0[nt] = __builtin_amdgcn_mfma_f32_16x16x32_bf16(a0, bw[nt], acc0[nt], 0, 0, 0);
            acc1[nt] = __builtin_amdgcn_mfma_f32_16x16x32_bf16(a1, bw[nt], acc1[nt], 0, 0, 0);
        }
    }

    // epilogue: both tiles; stats accumulated across tiles, one shfl pass
    #pragma unroll
    for (int nt = 0; nt < 8; nt++) {
        int n = nt * 16 + m;
        float bv = b0[n];
        unsigned u0 = packbf(acc0[nt][0] + bv, acc0[nt][1] + bv);
        unsigned u1 = packbf(acc0[nt][2] + bv, acc0[nt][3] + bv);
        unsigned u2 = packbf(acc1[nt][0] + bv, acc1[nt][1] + bv);
        unsigned u3 = packbf(acc1[nt][2] + bv, acc1[nt][3] + bv);
        int g0i = blk * 2;                      // tile64 ids: blk*2, blk*2+1
        y0w[((size_t)(g0i * 4 + wv) * 8 + nt) * 64 + lane]       = make_uint2(u0, u1);
        y0w[((size_t)((g0i + 1) * 4 + wv) * 8 + nt) * 64 + lane] = make_uint2(u2, u3);
        float v0 = bflo(u0), v1 = bfhi(u0), v2 = bflo(u1), v3 = bfhi(u1);
        float v4 = bflo(u2), v5 = bfhi(u2), v6 = bflo(u3), v7 = bfhi(u3);
        float s  = v0 + v1 + v2 + v3 + v4 + v5 + v6 + v7;
        float q2 = v0*v0 + v1*v1 + v2*v2 + v3*v3 + v4*v4 + v5*v5 + v6*v6 + v7*v7;
        s += __shfl_xor(s, 16, 64); q2 += __shfl_xor(q2, 16, 64);
        s += __shfl_xor(s, 32, 64); q2 += __shfl_xor(q2, 32, 64);
        if (q == 0) { wsum[wv][n] = s; wsq[wv][n] = q2; }
    }
    __syncthreads();

    float* slot = slots0 + (size_t)(blk & (NSLOT - 1)) * 256;
    if (t < CM_)
        atomicAdd(&slot[t], wsum[0][t] + wsum[1][t] + wsum[2][t] + wsum[3][t]);
    else
        atomicAdd(&slot[t], wsq[0][t - CM_] + wsq[1][t - CM_] + wsq[2][t - CM_] + wsq[3][t - CM_]);
}

// ---------------------------------------------------------------------------
// K2: 128 points/block. Inline BN0 finalize from slots0 (L2-broadcast reads);
// y0 frags -> BN0+ReLU -> LDS A-tiles; MFMA matmul1 (2-tile B-reuse);
// y1 frag-packed bf16 + BN1 stats.
// ---------------------------------------------------------------------------
__global__ __launch_bounds__(256, 3) void fused2_kernel(
    const uint2* __restrict__ y0w, const float* __restrict__ slots0,
    const float* __restrict__ g0, const float* __restrict__ be0,
    const unsigned short* __restrict__ w1F, const float* __restrict__ b1,
    uint2* __restrict__ y1w, float* __restrict__ slots1)
{
    __shared__ unsigned short x1s[128][CM_ + 8];   // pitch 136 shorts
    __shared__ float scl[CM_], shf[CM_];
    __shared__ float wsum[4][CM_], wsq[4][CM_];

    const int t = threadIdx.x;
    const int blk = blockIdx.x;                 // 1024 blocks
    const int wv = t >> 6, lane = t & 63;
    const int m = lane & 15, q = lane >> 4;
    const int g0i = blk * 2;

    if (t < CM_) {                              // inline bnfin(slots0)
        float s = 0.f, q2 = 0.f;
        #pragma unroll
        for (int sl = 0; sl < NSLOT; sl++) {
            s  += slots0[sl * 256 + t];
            q2 += slots0[sl * 256 + CM_ + t];
        }
        const float invn = 1.0f / (float)NTOT;
        float mu = s * invn, var = q2 * invn - mu * mu;
        float sc = g0[t] * rsqrtf(var + BN_EPS_);
        scl[t] = sc; shf[t] = be0[t] - mu * sc;
    }
    __syncthreads();

    // y0 frags (both tiles) -> BN0+ReLU -> bf16 A-tiles in LDS
    #pragma unroll
    for (int nt = 0; nt < 8; nt++) {
        int n = nt * 16 + m;
        float sc = scl[n], sh = shf[n];
        uint2 ua = y0w[((size_t)(g0i * 4 + wv) * 8 + nt) * 64 + lane];
        uint2 ub = y0w[((size_t)((g0i + 1) * 4 + wv) * 8 + nt) * 64 + lane];
        int rb = wv * 16 + q * 4;
        x1s[rb + 0][n] = f2bf(fmaxf(bflo(ua.x) * sc + sh, 0.f));
        x1s[rb + 1][n] = f2bf(fmaxf(bfhi(ua.x) * sc + sh, 0.f));
        x1s[rb + 2][n] = f2bf(fmaxf(bflo(ua.y) * sc + sh, 0.f));
        x1s[rb + 3][n] = f2bf(fmaxf(bfhi(ua.y) * sc + sh, 0.f));
        x1s[64 + rb + 0][n] = f2bf(fmaxf(bflo(ub.x) * sc + sh, 0.f));
        x1s[64 + rb + 1][n] = f2bf(fmaxf(bfhi(ub.x) * sc + sh, 0.f));
        x1s[64 + rb + 2][n] = f2bf(fmaxf(bflo(ub.y) * sc + sh, 0.f));
        x1s[64 + rb + 3][n] = f2bf(fmaxf(bfhi(ub.y) * sc + sh, 0.f));
    }
    __syncthreads();

    const int lr0 = wv * 16 + m, lr1 = lr0 + 64;
    floatx4 acc0[8], acc1[8];
    #pragma unroll
    for (int nt = 0; nt < 8; nt++) {
        acc0[nt] = (floatx4){0.f, 0.f, 0.f, 0.f};
        acc1[nt] = (floatx4){0.f, 0.f, 0.f, 0.f};
    }

    #pragma unroll
    for (int kk = 0; kk < 4; kk++) {
        short8 bw[8];
        #pragma unroll
        for (int nt = 0; nt < 8; nt++)
            bw[nt] = *(const short8*)(w1F + ((size_t)(kk * 8 + nt) * 64 + lane) * 8);
        short8 a0 = *(const short8*)&x1s[lr0][kk * 32 + q * 8];
        short8 a1 = *(const short8*)&x1s[lr1][kk * 32 + q * 8];
        #pragma unroll
        for (int nt = 0; nt < 8; nt++) {
            acc0[nt] = __builtin_amdgcn_mfma_f32_16x16x32_bf16(a0, bw[nt], acc0[nt], 0, 0, 0);
            acc1[nt] = __builtin_amdgcn_mfma_f32_16x16x32_bf16(a1, bw[nt], acc1[nt], 0, 0, 0);
        }
    }

    #pragma unroll
    for (int nt = 0; nt < 8; nt++) {
        int n = nt * 16 + m;
        float bv = b1[n];
        unsigned u0 = packbf(acc0[nt][0] + bv, acc0[nt][1] + bv);
        unsigned u1 = packbf(acc0[nt][2] + bv, acc0[nt][3] + bv);
        unsigned u2 = packbf(acc1[nt][0] + bv, acc1[nt][1] + bv);
        unsigned u3 = packbf(acc1[nt][2] + bv, acc1[nt][3] + bv);
        y1w[((size_t)(g0i * 4 + wv) * 8 + nt) * 64 + lane]       = make_uint2(u0, u1);
        y1w[((size_t)((g0i + 1) * 4 + wv) * 8 + nt) * 64 + lane] = make_uint2(u2, u3);
        float v0 = bflo(u0), v1 = bfhi(u0), v2 = bflo(u1), v3 = bfhi(u1);
        float v4 = bflo(u2), v5 = bfhi(u2), v6 = bflo(u3), v7 = bfhi(u3);
        float s  = v0 + v1 + v2 + v3 + v4 + v5 + v6 + v7;
        float q2 = v0*v0 + v1*v1 + v2*v2 + v3*v3 + v4*v4 + v5*v5 + v6*v6 + v7*v7;
        s += __shfl_xor(s, 16, 64); q2 += __shfl_xor(q2, 16, 64);
        s += __shfl_xor(s, 32, 64); q2 += __shfl_xor(q2, 32, 64);
        if (q == 0) { wsum[wv][n] = s; wsq[wv][n] = q2; }
    }
    __syncthreads();

    float* slot = slots1 + (size_t)(blk & (NSLOT - 1)) * 256;
    if (t < CM_)
        atomicAdd(&slot[t], wsum[0][t] + wsum[1][t] + wsum[2][t] + wsum[3][t]);
    else
        atomicAdd(&slot[t], wsq[0][t - CM_] + wsq[1][t - CM_] + wsq[2][t - CM_] + wsq[3][t - CM_]);
}

// ---------------------------------------------------------------------------
// K3: 128 points/block. Inline BN1 finalize from slots1; y1 frags ->
// BN1+ReLU -> LDS transpose (2 tile passes) -> coalesced f32 row-major out.
// ---------------------------------------------------------------------------
__global__ __launch_bounds__(256) void bn_out_kernel(
    const uint2* __restrict__ y1w, const float* __restrict__ slots1,
    const float* __restrict__ g1, const float* __restrict__ be1,
    float* __restrict__ out)
{
    __shared__ float xo[64][CM_ + 12];    // pitch 140 floats
    __shared__ float scl[CM_], shf[CM_];
    const int t = threadIdx.x;
    const int blk = blockIdx.x;           // 1024 blocks, 128 pts each
    const int wv = t >> 6, lane = t & 63;
    const int m = lane & 15, q = lane >> 4;

    if (t < CM_) {                        // inline bnfin(slots1)
        float s = 0.f, q2 = 0.f;
        #pragma unroll
        for (int sl = 0; sl < NSLOT; sl++) {
            s  += slots1[sl * 256 + t];
            q2 += slots1[sl * 256 + CM_ + t];
        }
        const float invn = 1.0f / (float)NTOT;
        float mu = s * invn, var = q2 * invn - mu * mu;
        float sc = g1[t] * rsqrtf(var + BN_EPS_);
        scl[t] = sc; shf[t] = be1[t] - mu * sc;
    }
    __syncthreads();

    #pragma unroll
    for (int tile = 0; tile < 2; tile++) {
        const int g = blk * 2 + tile;
        #pragma unroll
        for (int nt = 0; nt < 8; nt++) {
            int n = nt * 16 + m;
            float sc = scl[n], sh = shf[n];
            uint2 u = y1w[((size_t)(g * 4 + wv) * 8 + nt) * 64 + lane];
            int rb = wv * 16 + q * 4;
            xo[rb + 0][n] = fmaxf(bflo(u.x) * sc + sh, 0.f);
            xo[rb + 1][n] = fmaxf(bfhi(u.x) * sc + sh, 0.f);
            xo[rb + 2][n] = fmaxf(bflo(u.y) * sc + sh, 0.f);
            xo[rb + 3][n] = fmaxf(bfhi(u.y) * sc + sh, 0.f);
        }
        __syncthreads();
        const int pbase = g * 64;
        #pragma unroll
        for (int i = 0; i < 8; i++) {
            int idx = t + i * 256;
            int p = idx >> 5, c4 = (idx & 31) << 2;
            float4 v = *(const float4*)&xo[p][c4];
            *(float4*)(out + (size_t)(pbase + p) * CM_ + c4) = v;
        }
        __syncthreads();                  // xo reused next tile
    }
}

// ---------------------------------------------------------------------------
extern "C" void kernel_launch(void* const* d_in, const int* in_sizes, int n_in,
                              void* d_out, int out_size, void* d_ws, size_t ws_size,
                              hipStream_t stream)
{
    const float* xyz1  = (const float*)d_in[0];
    const float* xyz2  = (const float*)d_in[1];
    const float* feat1 = (const float*)d_in[2];
    const float* feat2 = (const float*)d_in[3];
    const float* w0    = (const float*)d_in[4];
    const float* b0    = (const float*)d_in[5];
    const float* g0    = (const float*)d_in[6];
    const float* be0   = (const float*)d_in[7];
    const float* w1    = (const float*)d_in[8];
    const float* b1    = (const float*)d_in[9];
    const float* g1    = (const float*)d_in[10];
    const float* be1   = (const float*)d_in[11];
    float* out = (float*)d_out;

    char* ws = (char*)d_ws;
    // ws: slots0 32K | slots1 32K | w0F 48K | w1F 32K | y0w 33.5M | y1w 33.5M
    float* slots0       = (float*)(ws);
    float* slots1       = (float*)(ws + (size_t)NSLOT * 256 * 4);
    char*  p            = ws + 2 * (size_t)NSLOT * 256 * 4;
    unsigned short* w0F = (unsigned short*)p;  p += (size_t)CIN_ * CM_ * 2;
    unsigned short* w1F = (unsigned short*)p;  p += (size_t)CM_ * CM_ * 2;
    uint2* y0w          = (uint2*)p;           p += (size_t)NTOT * CM_ * 2;
    uint2* y1w          = (uint2*)p;

    hipMemsetAsync(ws, 0, 2 * (size_t)NSLOT * 256 * 4, stream);  // zero stat slots

    prepw_kernel<<<20, 256, 0, stream>>>(w0, w1, w0F, w1F);
    fused1_kernel<<<NTOT / 128, 256, 0, stream>>>(xyz1, xyz2, feat1, feat2,
                                                  w0F, b0, y0w, slots0);
    fused2_kernel<<<NTOT / 128, 256, 0, stream>>>(y0w, slots0, g0, be0,
                                                  w1F, b1, y1w, slots1);
    bn_out_kernel<<<NTOT / 128, 256, 0, stream>>>(y1w, slots1, g1, be1, out);
}